// Round 1
// baseline (1355.811 us; speedup 1.0000x reference)
//
#include <hip/hip_runtime.h>
#include <cstdint>

#define NT   16384
#define DIN  1024
#define DHID 4096
#define DOUT 1024
#define NE   8

typedef unsigned short u16;
typedef short bf16x8 __attribute__((ext_vector_type(8)));
typedef float f32x4  __attribute__((ext_vector_type(4)));

__device__ __forceinline__ u16 f2b(float f) {
  union { float f; unsigned u; } a; a.f = f;
  unsigned u = a.u;
  return (u16)((u + 0x7FFFu + ((u >> 16) & 1u)) >> 16);  // RNE
}

// ---------------- router: logits, argmax, bf16 copy of x ----------------
__global__ void router_kernel(const float* __restrict__ x, const float* __restrict__ Wr,
                              const float* __restrict__ br, u16* __restrict__ Xb,
                              int* __restrict__ eidx, int* __restrict__ counts) {
  int t = blockIdx.x * 4 + (threadIdx.x >> 6);
  int lane = threadIdx.x & 63;
  const float* xr = x + (size_t)t * DIN;
  u16* xbr = Xb + (size_t)t * DIN;
  float acc[NE];
#pragma unroll
  for (int e = 0; e < NE; e++) acc[e] = 0.f;
#pragma unroll
  for (int i = 0; i < DIN / 64; i++) {
    int k = lane + i * 64;
    float xv = xr[k];
    xbr[k] = f2b(xv);
    const float4 w0 = *(const float4*)(Wr + (size_t)k * NE);
    const float4 w1 = *(const float4*)(Wr + (size_t)k * NE + 4);
    acc[0] += xv * w0.x; acc[1] += xv * w0.y; acc[2] += xv * w0.z; acc[3] += xv * w0.w;
    acc[4] += xv * w1.x; acc[5] += xv * w1.y; acc[6] += xv * w1.z; acc[7] += xv * w1.w;
  }
#pragma unroll
  for (int off = 32; off > 0; off >>= 1) {
#pragma unroll
    for (int e = 0; e < NE; e++) acc[e] += __shfl_down(acc[e], off, 64);
  }
  if (lane == 0) {
    int best = 0; float bv = acc[0] + br[0];
#pragma unroll
    for (int e = 1; e < NE; e++) {
      float v = acc[e] + br[e];
      if (v > bv) { bv = v; best = e; }   // strict > keeps first max (jnp.argmax)
    }
    eidx[t] = best;
    atomicAdd(&counts[best], 1);
  }
}

__global__ void zero_kernel(int* __restrict__ p) {
  if (threadIdx.x < 16) p[threadIdx.x] = 0;   // counts[8] + cursor[8]
}

__global__ void scan_kernel(const int* __restrict__ counts, int* __restrict__ offsets) {
  if (threadIdx.x == 0) {
    int s = 0;
    for (int e = 0; e < NE; e++) { offsets[e] = s; s += counts[e]; }
    offsets[NE] = s;
  }
}

__global__ void scatter_kernel(const int* __restrict__ eidx, const int* __restrict__ offsets,
                               int* __restrict__ cursor, int* __restrict__ perm) {
  int t = blockIdx.x * blockDim.x + threadIdx.x;
  if (t >= NT) return;
  int e = eidx[t];
  int pos = offsets[e] + atomicAdd(&cursor[e], 1);
  perm[pos] = t;
}

// ------------- convert fp32 W[E][K][H] -> bf16 Wt[E][H][K] --------------
__global__ void transpose_cvt_kernel(const float* __restrict__ W, u16* __restrict__ Wt,
                                     int K, int H) {
  __shared__ float tile[64][65];
  const int e = blockIdx.z;
  const int k0 = blockIdx.x * 64, h0 = blockIdx.y * 64;
  const float* src = W + (size_t)e * K * H;
  u16* dst = Wt + (size_t)e * K * H;
  const int tid = threadIdx.x;
#pragma unroll
  for (int i = 0; i < 4; i++) {
    int idx = tid + i * 256;          // 1024 float4 chunks = 64x64 floats
    int r = idx >> 4;                 // k-row within tile
    int c = (idx & 15) * 4;           // h-col within tile
    const float4 v = *(const float4*)(src + (size_t)(k0 + r) * H + h0 + c);
    tile[r][c] = v.x; tile[r][c + 1] = v.y; tile[r][c + 2] = v.z; tile[r][c + 3] = v.w;
  }
  __syncthreads();
#pragma unroll
  for (int i = 0; i < 4; i++) {
    int idx = tid + i * 256;
    int r = idx >> 4;                 // h-row within tile
    int c = (idx & 15) * 4;           // k-col within tile
    ushort4 o;
    o.x = f2b(tile[c][r]); o.y = f2b(tile[c + 1][r]);
    o.z = f2b(tile[c + 2][r]); o.w = f2b(tile[c + 3][r]);
    *(ushort4*)(dst + (size_t)(h0 + r) * K + k0 + c) = o;
  }
}

// ---------------- grouped GEMM: 128x128 tile, 16x16x32 bf16 MFMA --------
// A: bf16 [*, K] rows (gathered via perm for GEMM1; contiguous for GEMM2)
// Bt: bf16 [E][N][K] (B transposed, K-innermost)
template<bool GATHER_A, bool STORE_HIDDEN>
__global__ __launch_bounds__(256, 2) void moe_gemm(
    const u16* __restrict__ A, const u16* __restrict__ Bt,
    const float* __restrict__ bias,
    const int* __restrict__ perm, const int* __restrict__ counts,
    const int* __restrict__ offsets,
    u16* __restrict__ Hout, float* __restrict__ Fout,
    int K, int N) {
  const int e = blockIdx.z;
  const int cnt = counts[e];
  const int m0 = blockIdx.y * 128;
  if (m0 >= cnt) return;
  int valid = cnt - m0; if (valid > 128) valid = 128;
  const int base_p = offsets[e] + m0;
  const int n0 = blockIdx.x * 128;

  // LDS tiles padded to 40 u16/row (80 B) -> conflict-light b128 access
  __shared__ u16 sA[128 * 40];
  __shared__ u16 sB[128 * 40];

  const int tid = threadIdx.x;
  const int lane = tid & 63;
  const int wave = tid >> 6;
  const int wm = (wave >> 1) * 64;
  const int wn = (wave & 1) * 64;
  const int quad = lane >> 4;
  const int l15 = lane & 15;

  // staging: 256 threads, each covers (row = tid&127, k-half = tid>>7) = 32 B
  const int srow = tid & 127;
  const int shalf = (tid >> 7) * 16;

  int p = base_p + srow;
  if (p > NT - 1) p = NT - 1;          // clamp tail (masked at store)
  const int arow = GATHER_A ? perm[p] : p;
  const u16* aptr = A + (size_t)arow * K + shalf;
  const u16* bptr = Bt + ((size_t)e * N + n0 + srow) * K + shalf;
  u16* sAw = &sA[srow * 40 + shalf];
  u16* sBw = &sB[srow * 40 + shalf];

  f32x4 acc[4][4];
#pragma unroll
  for (int mi = 0; mi < 4; mi++)
#pragma unroll
    for (int ni = 0; ni < 4; ni++)
      acc[mi][ni] = (f32x4){0.f, 0.f, 0.f, 0.f};

  const int kiters = K >> 5;           // BK = 32
  for (int kt = 0; kt < kiters; kt++) {
    const uint4 a0 = *(const uint4*)(aptr);
    const uint4 a1 = *(const uint4*)(aptr + 8);
    const uint4 b0 = *(const uint4*)(bptr);
    const uint4 b1 = *(const uint4*)(bptr + 8);
    aptr += 32; bptr += 32;
    if (kt) __syncthreads();
    *(uint4*)sAw = a0; *(uint4*)(sAw + 8) = a1;
    *(uint4*)sBw = b0; *(uint4*)(sBw + 8) = b1;
    __syncthreads();
    bf16x8 af[4], bfr[4];
#pragma unroll
    for (int mi = 0; mi < 4; mi++)
      af[mi] = *(const bf16x8*)&sA[(wm + mi * 16 + l15) * 40 + quad * 8];
#pragma unroll
    for (int ni = 0; ni < 4; ni++)
      bfr[ni] = *(const bf16x8*)&sB[(wn + ni * 16 + l15) * 40 + quad * 8];
#pragma unroll
    for (int mi = 0; mi < 4; mi++)
#pragma unroll
      for (int ni = 0; ni < 4; ni++)
        acc[mi][ni] = __builtin_amdgcn_mfma_f32_16x16x32_bf16(af[mi], bfr[ni], acc[mi][ni], 0, 0, 0);
  }

  float bv[4];
#pragma unroll
  for (int ni = 0; ni < 4; ni++)
    bv[ni] = bias[(size_t)e * N + n0 + wn + ni * 16 + l15];

  // C/D layout (m89-verified): col = lane&15, row = quad*4 + r
#pragma unroll
  for (int mi = 0; mi < 4; mi++) {
#pragma unroll
    for (int r = 0; r < 4; r++) {
      const int ml = wm + mi * 16 + quad * 4 + r;
      if (ml >= valid) continue;
      const int pp = base_p + ml;
      if (STORE_HIDDEN) {
        u16* orow = Hout + (size_t)pp * N + n0 + wn;
#pragma unroll
        for (int ni = 0; ni < 4; ni++) {
          float v = acc[mi][ni][r] + bv[ni];
          v = v > 0.f ? v : 0.f;
          orow[ni * 16 + l15] = f2b(v);
        }
      } else {
        const int token = perm[pp];
        float* orow = Fout + (size_t)token * N + n0 + wn;
#pragma unroll
        for (int ni = 0; ni < 4; ni++)
          orow[ni * 16 + l15] = acc[mi][ni][r] + bv[ni];
      }
    }
  }
}

__global__ void sentinel_kernel(float* __restrict__ out, int n) {
  int i = blockIdx.x * blockDim.x + threadIdx.x;
  if (i < n) out[i] = 31337.0f;   // diagnoses ws_size too small via absmax
}

extern "C" void kernel_launch(void* const* d_in, const int* in_sizes, int n_in,
                              void* d_out, int out_size, void* d_ws, size_t ws_size,
                              hipStream_t stream) {
  const float* x  = (const float*)d_in[0];
  const float* Wr = (const float*)d_in[1];
  const float* br = (const float*)d_in[2];
  const float* W1 = (const float*)d_in[3];
  const float* b1 = (const float*)d_in[4];
  const float* W2 = (const float*)d_in[5];
  const float* b2 = (const float*)d_in[6];
  float* out = (float*)d_out;

  // workspace layout
  const size_t szXb  = (size_t)NT * DIN * 2;          // 33,554,432
  const size_t szW1t = (size_t)NE * DIN * DHID * 2;   // 67,108,864
  const size_t szW2t = (size_t)NE * DHID * DOUT * 2;  // 67,108,864
  const size_t szHid = (size_t)NT * DHID * 2;         // 134,217,728
  char* ws = (char*)d_ws;
  u16* Xb   = (u16*)ws;
  u16* W1t  = (u16*)(ws + szXb);
  u16* W2t  = (u16*)(ws + szXb + szW1t);
  u16* Hid  = (u16*)(ws + szXb + szW1t + szW2t);
  int* perm = (int*)(ws + szXb + szW1t + szW2t + szHid);
  int* eidx = perm + NT;
  int* ctrl = eidx + NT;          // counts[8] | cursor[8] | offsets[9]
  int* counts  = ctrl;
  int* cursor  = ctrl + 8;
  int* offsets = ctrl + 16;
  const size_t NEED = szXb + szW1t + szW2t + szHid + (size_t)NT * 4 * 2 + 256;

  if (ws_size < NEED) {
    sentinel_kernel<<<(out_size + 255) / 256, 256, 0, stream>>>(out, out_size);
    return;
  }

  zero_kernel<<<1, 64, 0, stream>>>(ctrl);
  transpose_cvt_kernel<<<dim3(DIN / 64, DHID / 64, NE), 256, 0, stream>>>(W1, W1t, DIN, DHID);
  transpose_cvt_kernel<<<dim3(DHID / 64, DOUT / 64, NE), 256, 0, stream>>>(W2, W2t, DHID, DOUT);
  router_kernel<<<NT / 4, 256, 0, stream>>>(x, Wr, br, Xb, eidx, counts);
  scan_kernel<<<1, 64, 0, stream>>>(counts, offsets);
  scatter_kernel<<<NT / 256, 256, 0, stream>>>(eidx, offsets, cursor, perm);

  // GEMM1: hidden[p][h] = relu(Xb[perm[p]] @ W1[e] + b1[e]), bf16
  moe_gemm<true, true><<<dim3(DHID / 128, NT / 128, NE), 256, 0, stream>>>(
      Xb, W1t, b1, perm, counts, offsets, Hid, nullptr, DIN, DHID);
  // GEMM2: out[perm[p]][o] = hidden[p] @ W2[e] + b2[e], fp32
  moe_gemm<false, false><<<dim3(DOUT / 128, NT / 128, NE), 256, 0, stream>>>(
      Hid, W2t, b2, perm, counts, offsets, nullptr, out, DHID, DOUT);
}

// Round 2
// 1065.749 us; speedup vs baseline: 1.2722x; 1.2722x over previous
//
#include <hip/hip_runtime.h>
#include <cstdint>

#define NT   16384
#define DIN  1024
#define DHID 4096
#define DOUT 1024
#define NE   8

typedef unsigned short u16;
typedef short bf16x8 __attribute__((ext_vector_type(8)));
typedef float f32x4  __attribute__((ext_vector_type(4)));

__device__ __forceinline__ u16 f2b(float f) {
  union { float f; unsigned u; } a; a.f = f;
  unsigned u = a.u;
  return (u16)((u + 0x7FFFu + ((u >> 16) & 1u)) >> 16);  // RNE
}

// async global->LDS, 16B per lane; LDS dst must be wave-uniform base (lane*16 auto)
__device__ __forceinline__ void gl_lds16(const u16* g, u16* l) {
  __builtin_amdgcn_global_load_lds(
      (const __attribute__((address_space(1))) void*)g,
      (__attribute__((address_space(3))) void*)l,
      16, 0, 0);
}

// ---------------- router: logits, argmax, bf16 copy of x ----------------
__global__ void router_kernel(const float* __restrict__ x, const float* __restrict__ Wr,
                              const float* __restrict__ br, u16* __restrict__ Xb,
                              int* __restrict__ eidx, int* __restrict__ counts) {
  int t = blockIdx.x * 4 + (threadIdx.x >> 6);
  int lane = threadIdx.x & 63;
  const float* xr = x + (size_t)t * DIN;
  u16* xbr = Xb + (size_t)t * DIN;
  float acc[NE];
#pragma unroll
  for (int e = 0; e < NE; e++) acc[e] = 0.f;
#pragma unroll
  for (int i = 0; i < DIN / 64; i++) {
    int k = lane + i * 64;
    float xv = xr[k];
    xbr[k] = f2b(xv);
    const float4 w0 = *(const float4*)(Wr + (size_t)k * NE);
    const float4 w1 = *(const float4*)(Wr + (size_t)k * NE + 4);
    acc[0] += xv * w0.x; acc[1] += xv * w0.y; acc[2] += xv * w0.z; acc[3] += xv * w0.w;
    acc[4] += xv * w1.x; acc[5] += xv * w1.y; acc[6] += xv * w1.z; acc[7] += xv * w1.w;
  }
#pragma unroll
  for (int off = 32; off > 0; off >>= 1) {
#pragma unroll
    for (int e = 0; e < NE; e++) acc[e] += __shfl_down(acc[e], off, 64);
  }
  if (lane == 0) {
    int best = 0; float bv = acc[0] + br[0];
#pragma unroll
    for (int e = 1; e < NE; e++) {
      float v = acc[e] + br[e];
      if (v > bv) { bv = v; best = e; }   // strict > keeps first max (jnp.argmax)
    }
    eidx[t] = best;
    atomicAdd(&counts[best], 1);
  }
}

__global__ void zero_kernel(int* __restrict__ p) {
  if (threadIdx.x < 16) p[threadIdx.x] = 0;   // counts[8] + cursor[8]
}

__global__ void scan_kernel(const int* __restrict__ counts, int* __restrict__ offsets) {
  if (threadIdx.x == 0) {
    int s = 0;
    for (int e = 0; e < NE; e++) { offsets[e] = s; s += counts[e]; }
    offsets[NE] = s;
  }
}

__global__ void scatter_kernel(const int* __restrict__ eidx, const int* __restrict__ offsets,
                               int* __restrict__ cursor, int* __restrict__ perm) {
  int t = blockIdx.x * blockDim.x + threadIdx.x;
  if (t >= NT) return;
  int e = eidx[t];
  int pos = offsets[e] + atomicAdd(&cursor[e], 1);
  perm[pos] = t;
}

// ------------- convert fp32 W[E][K][H] -> bf16 Wt[E][H][K] --------------
__global__ void transpose_cvt_kernel(const float* __restrict__ W, u16* __restrict__ Wt,
                                     int K, int H) {
  __shared__ float tile[64][65];
  const int e = blockIdx.z;
  const int k0 = blockIdx.x * 64, h0 = blockIdx.y * 64;
  const float* src = W + (size_t)e * K * H;
  u16* dst = Wt + (size_t)e * K * H;
  const int tid = threadIdx.x;
#pragma unroll
  for (int i = 0; i < 4; i++) {
    int idx = tid + i * 256;          // 1024 float4 chunks = 64x64 floats
    int r = idx >> 4;                 // k-row within tile
    int c = (idx & 15) * 4;           // h-col within tile
    const float4 v = *(const float4*)(src + (size_t)(k0 + r) * H + h0 + c);
    tile[r][c] = v.x; tile[r][c + 1] = v.y; tile[r][c + 2] = v.z; tile[r][c + 3] = v.w;
  }
  __syncthreads();
#pragma unroll
  for (int i = 0; i < 4; i++) {
    int idx = tid + i * 256;
    int r = idx >> 4;                 // h-row within tile
    int c = (idx & 15) * 4;           // k-col within tile
    ushort4 o;
    o.x = f2b(tile[c][r]); o.y = f2b(tile[c + 1][r]);
    o.z = f2b(tile[c + 2][r]); o.w = f2b(tile[c + 3][r]);
    *(ushort4*)(dst + (size_t)(h0 + r) * K + k0 + c) = o;
  }
}

// ---------------- grouped GEMM: 128x128 tile, 16x16x32 bf16 MFMA --------
// m97 structure: global_load_lds width=16 staging, unpadded LDS [128][32],
// 2-barrier K-loop, 4 waves x (4x4) 16x16x32 frags.
// A: bf16 [*, K] rows (gathered via perm for GEMM1; contiguous for GEMM2)
// Bt: bf16 [E][N][K] (B transposed, K-innermost)
template<bool GATHER_A, bool STORE_HIDDEN>
__global__ __launch_bounds__(256, 2) void moe_gemm(
    const u16* __restrict__ A, const u16* __restrict__ Bt,
    const float* __restrict__ bias,
    const int* __restrict__ perm, const int* __restrict__ counts,
    const int* __restrict__ offsets,
    u16* __restrict__ Hout, float* __restrict__ Fout,
    int K, int N) {
  const int e = blockIdx.z;
  const int cnt = counts[e];
  const int m0 = blockIdx.y * 128;
  if (m0 >= cnt) return;
  int valid = cnt - m0; if (valid > 128) valid = 128;
  const int base_p = offsets[e] + m0;
  const int n0 = blockIdx.x * 128;

  // Unpadded: global_load_lds requires LDS contiguous in lane order.
  __shared__ u16 sA[128 * 32];   // 8 KB
  __shared__ u16 sB[128 * 32];   // 8 KB

  const int tid = threadIdx.x;
  const int lane = tid & 63;
  const int wave = tid >> 6;
  const int wm = (wave >> 1) * 64;
  const int wn = (wave & 1) * 64;
  const int quad = lane >> 4;
  const int l15 = lane & 15;

  // staging map: chunk c (0..7) of a tile = rows 16c..16c+15, 1024 B LDS.
  // wave w issues chunks {w, w+4}. lane i: row = 16c + i/4, col = (i%4)*8 elems.
  const int rr = lane >> 2;           // 0..15 row within chunk
  const int cb = (lane & 3) * 8;      // k-offset (elems) within row

  const int rA0 = wave * 16 + rr;
  const int rA1 = rA0 + 64;

  int pa0 = base_p + rA0; if (pa0 > NT - 1) pa0 = NT - 1;   // tail clamp (masked at store)
  int pa1 = base_p + rA1; if (pa1 > NT - 1) pa1 = NT - 1;
  const int arow0 = GATHER_A ? perm[pa0] : pa0;
  const int arow1 = GATHER_A ? perm[pa1] : pa1;
  const u16* aptr0 = A + (size_t)arow0 * K + cb;
  const u16* aptr1 = A + (size_t)arow1 * K + cb;
  const u16* bptr0 = Bt + ((size_t)e * N + n0 + rA0) * K + cb;
  const u16* bptr1 = Bt + ((size_t)e * N + n0 + rA1) * K + cb;

  u16* dA0 = &sA[wave * 512];          // chunk w      (bytes: wave*1024)
  u16* dA1 = &sA[wave * 512 + 2048];   // chunk w+4
  u16* dB0 = &sB[wave * 512];
  u16* dB1 = &sB[wave * 512 + 2048];

  f32x4 acc[4][4];
#pragma unroll
  for (int mi = 0; mi < 4; mi++)
#pragma unroll
    for (int ni = 0; ni < 4; ni++)
      acc[mi][ni] = (f32x4){0.f, 0.f, 0.f, 0.f};

  const int kiters = K >> 5;           // BK = 32
  for (int kt = 0; kt < kiters; kt++) {
    if (kt) __syncthreads();           // frags of kt-1 consumed before overwrite
    gl_lds16(aptr0, dA0);
    gl_lds16(aptr1, dA1);
    gl_lds16(bptr0, dB0);
    gl_lds16(bptr1, dB1);
    aptr0 += 32; aptr1 += 32; bptr0 += 32; bptr1 += 32;
    __syncthreads();                   // drains vmcnt -> tiles resident

    bf16x8 af[4], bfr[4];
#pragma unroll
    for (int mi = 0; mi < 4; mi++)
      af[mi] = *(const bf16x8*)&sA[(wm + mi * 16 + l15) * 32 + quad * 8];
#pragma unroll
    for (int ni = 0; ni < 4; ni++)
      bfr[ni] = *(const bf16x8*)&sB[(wn + ni * 16 + l15) * 32 + quad * 8];
#pragma unroll
    for (int mi = 0; mi < 4; mi++)
#pragma unroll
      for (int ni = 0; ni < 4; ni++)
        acc[mi][ni] = __builtin_amdgcn_mfma_f32_16x16x32_bf16(af[mi], bfr[ni], acc[mi][ni], 0, 0, 0);
  }

  float bv[4];
#pragma unroll
  for (int ni = 0; ni < 4; ni++)
    bv[ni] = bias[(size_t)e * N + n0 + wn + ni * 16 + l15];

  // C/D layout (m89-verified): col = lane&15, row = quad*4 + r
#pragma unroll
  for (int mi = 0; mi < 4; mi++) {
#pragma unroll
    for (int r = 0; r < 4; r++) {
      const int ml = wm + mi * 16 + quad * 4 + r;
      if (ml >= valid) continue;
      const int pp = base_p + ml;
      if (STORE_HIDDEN) {
        u16* orow = Hout + (size_t)pp * N + n0 + wn;
#pragma unroll
        for (int ni = 0; ni < 4; ni++) {
          float v = acc[mi][ni][r] + bv[ni];
          v = v > 0.f ? v : 0.f;
          orow[ni * 16 + l15] = f2b(v);
        }
      } else {
        const int token = perm[pp];
        float* orow = Fout + (size_t)token * N + n0 + wn;
#pragma unroll
        for (int ni = 0; ni < 4; ni++)
          orow[ni * 16 + l15] = acc[mi][ni][r] + bv[ni];
      }
    }
  }
}

__global__ void sentinel_kernel(float* __restrict__ out, int n) {
  int i = blockIdx.x * blockDim.x + threadIdx.x;
  if (i < n) out[i] = 31337.0f;   // diagnoses ws_size too small via absmax
}

extern "C" void kernel_launch(void* const* d_in, const int* in_sizes, int n_in,
                              void* d_out, int out_size, void* d_ws, size_t ws_size,
                              hipStream_t stream) {
  const float* x  = (const float*)d_in[0];
  const float* Wr = (const float*)d_in[1];
  const float* br = (const float*)d_in[2];
  const float* W1 = (const float*)d_in[3];
  const float* b1 = (const float*)d_in[4];
  const float* W2 = (const float*)d_in[5];
  const float* b2 = (const float*)d_in[6];
  float* out = (float*)d_out;

  // workspace layout
  const size_t szXb  = (size_t)NT * DIN * 2;          // 33,554,432
  const size_t szW1t = (size_t)NE * DIN * DHID * 2;   // 67,108,864
  const size_t szW2t = (size_t)NE * DHID * DOUT * 2;  // 67,108,864
  const size_t szHid = (size_t)NT * DHID * 2;         // 134,217,728
  char* ws = (char*)d_ws;
  u16* Xb   = (u16*)ws;
  u16* W1t  = (u16*)(ws + szXb);
  u16* W2t  = (u16*)(ws + szXb + szW1t);
  u16* Hid  = (u16*)(ws + szXb + szW1t + szW2t);
  int* perm = (int*)(ws + szXb + szW1t + szW2t + szHid);
  int* eidx = perm + NT;
  int* ctrl = eidx + NT;          // counts[8] | cursor[8] | offsets[9]
  int* counts  = ctrl;
  int* cursor  = ctrl + 8;
  int* offsets = ctrl + 16;
  const size_t NEED = szXb + szW1t + szW2t + szHid + (size_t)NT * 4 * 2 + 256;

  if (ws_size < NEED) {
    sentinel_kernel<<<(out_size + 255) / 256, 256, 0, stream>>>(out, out_size);
    return;
  }

  zero_kernel<<<1, 64, 0, stream>>>(ctrl);
  transpose_cvt_kernel<<<dim3(DIN / 64, DHID / 64, NE), 256, 0, stream>>>(W1, W1t, DIN, DHID);
  transpose_cvt_kernel<<<dim3(DHID / 64, DOUT / 64, NE), 256, 0, stream>>>(W2, W2t, DHID, DOUT);
  router_kernel<<<NT / 4, 256, 0, stream>>>(x, Wr, br, Xb, eidx, counts);
  scan_kernel<<<1, 64, 0, stream>>>(counts, offsets);
  scatter_kernel<<<NT / 256, 256, 0, stream>>>(eidx, offsets, cursor, perm);

  // GEMM1: hidden[p][h] = relu(Xb[perm[p]] @ W1[e] + b1[e]), bf16
  moe_gemm<true, true><<<dim3(DHID / 128, NT / 128, NE), 256, 0, stream>>>(
      Xb, W1t, b1, perm, counts, offsets, Hid, nullptr, DIN, DHID);
  // GEMM2: out[perm[p]][o] = hidden[p] @ W2[e] + b2[e], fp32
  moe_gemm<false, false><<<dim3(DOUT / 128, NT / 128, NE), 256, 0, stream>>>(
      Hid, W2t, b2, perm, counts, offsets, nullptr, out, DHID, DOUT);
}

// Round 3
// 1014.715 us; speedup vs baseline: 1.3361x; 1.0503x over previous
//
#include <hip/hip_runtime.h>
#include <cstdint>

#define NT   16384
#define DIN  1024
#define DHID 4096
#define DOUT 1024
#define NE   8
#define NMT  136   // max m-tiles: NT/128 + NE

typedef unsigned short u16;
typedef short bf16x8 __attribute__((ext_vector_type(8)));
typedef float f32x4  __attribute__((ext_vector_type(4)));

__device__ __forceinline__ u16 f2b(float f) {
  union { float f; unsigned u; } a; a.f = f;
  unsigned u = a.u;
  return (u16)((u + 0x7FFFu + ((u >> 16) & 1u)) >> 16);  // RNE
}

// async global->LDS, 16B per lane; LDS dst is wave-uniform base + lane*16
__device__ __forceinline__ void gl_lds16(const u16* g, u16* l) {
  __builtin_amdgcn_global_load_lds(
      (const __attribute__((address_space(1))) void*)g,
      (__attribute__((address_space(3))) void*)l,
      16, 0, 0);
}

// ---------------- router: logits, argmax, bf16 copy of x ----------------
__global__ void router_kernel(const float* __restrict__ x, const float* __restrict__ Wr,
                              const float* __restrict__ br, u16* __restrict__ Xb,
                              int* __restrict__ eidx, int* __restrict__ counts) {
  int t = blockIdx.x * 4 + (threadIdx.x >> 6);
  int lane = threadIdx.x & 63;
  const float* xr = x + (size_t)t * DIN;
  u16* xbr = Xb + (size_t)t * DIN;
  float acc[NE];
#pragma unroll
  for (int e = 0; e < NE; e++) acc[e] = 0.f;
#pragma unroll
  for (int i = 0; i < DIN / 64; i++) {
    int k = lane + i * 64;
    float xv = xr[k];
    xbr[k] = f2b(xv);
    const float4 w0 = *(const float4*)(Wr + (size_t)k * NE);
    const float4 w1 = *(const float4*)(Wr + (size_t)k * NE + 4);
    acc[0] += xv * w0.x; acc[1] += xv * w0.y; acc[2] += xv * w0.z; acc[3] += xv * w0.w;
    acc[4] += xv * w1.x; acc[5] += xv * w1.y; acc[6] += xv * w1.z; acc[7] += xv * w1.w;
  }
#pragma unroll
  for (int off = 32; off > 0; off >>= 1) {
#pragma unroll
    for (int e = 0; e < NE; e++) acc[e] += __shfl_down(acc[e], off, 64);
  }
  if (lane == 0) {
    int best = 0; float bv = acc[0] + br[0];
#pragma unroll
    for (int e = 1; e < NE; e++) {
      float v = acc[e] + br[e];
      if (v > bv) { bv = v; best = e; }   // strict > keeps first max (jnp.argmax)
    }
    eidx[t] = best;
    atomicAdd(&counts[best], 1);
  }
}

__global__ void zero_kernel(int* __restrict__ p) {
  if (threadIdx.x < 16) p[threadIdx.x] = 0;   // counts[8] + cursor[8]
}

// prefix-scan + build compact (expert, row-base, valid) tile map
__global__ void scan_kernel(const int* __restrict__ counts, int* __restrict__ offsets,
                            int4* __restrict__ tiles) {
  if (threadIdx.x == 0) {
    int s = 0, nt = 0;
    for (int e = 0; e < NE; e++) {
      int c = counts[e];
      offsets[e] = s;
      for (int m0 = 0; m0 < c; m0 += 128) {
        int v = c - m0; if (v > 128) v = 128;
        tiles[nt++] = make_int4(e, s + m0, v, 0);
      }
      s += c;
    }
    offsets[NE] = s;
    while (nt < NMT) tiles[nt++] = make_int4(0, 0, 0, 0);
  }
}

__global__ void scatter_kernel(const int* __restrict__ eidx, const int* __restrict__ offsets,
                               int* __restrict__ cursor, int* __restrict__ perm) {
  int t = blockIdx.x * blockDim.x + threadIdx.x;
  if (t >= NT) return;
  int e = eidx[t];
  int pos = offsets[e] + atomicAdd(&cursor[e], 1);
  perm[pos] = t;
}

// ------------- convert fp32 W[E][K][H] -> bf16 Wt[E][H][K] --------------
__global__ void transpose_cvt_kernel(const float* __restrict__ W, u16* __restrict__ Wt,
                                     int K, int H) {
  __shared__ float tile[64][65];
  const int e = blockIdx.z;
  const int k0 = blockIdx.x * 64, h0 = blockIdx.y * 64;
  const float* src = W + (size_t)e * K * H;
  u16* dst = Wt + (size_t)e * K * H;
  const int tid = threadIdx.x;
#pragma unroll
  for (int i = 0; i < 4; i++) {
    int idx = tid + i * 256;          // 1024 float4 chunks = 64x64 floats
    int r = idx >> 4;                 // k-row within tile
    int c = (idx & 15) * 4;           // h-col within tile
    const float4 v = *(const float4*)(src + (size_t)(k0 + r) * H + h0 + c);
    tile[r][c] = v.x; tile[r][c + 1] = v.y; tile[r][c + 2] = v.z; tile[r][c + 3] = v.w;
  }
  __syncthreads();
#pragma unroll
  for (int i = 0; i < 4; i++) {
    int idx = tid + i * 256;
    int r = idx >> 4;                 // h-row within tile
    int c = (idx & 15) * 4;           // k-col within tile
    ushort4 o;
    o.x = f2b(tile[c][r]); o.y = f2b(tile[c + 1][r]);
    o.z = f2b(tile[c + 2][r]); o.w = f2b(tile[c + 3][r]);
    *(ushort4*)(dst + (size_t)(h0 + r) * K + k0 + c) = o;
  }
}

// ---------------- grouped GEMM: 128x128 tile, BK=64, 16x16x32 bf16 MFMA ----
// Split-half LDS layout [2][128][32] per operand (stride-32 per half = m97's
// proven bank pattern; global_load_lds forbids padding).
// A: bf16 [*, K] rows (gathered via perm for GEMM1; contiguous for GEMM2)
// Bt: bf16 [E][N][K] (B transposed, K-innermost)
template<bool GATHER_A, bool STORE_HIDDEN>
__global__ __launch_bounds__(256) void moe_gemm(
    const u16* __restrict__ A, const u16* __restrict__ Bt,
    const float* __restrict__ bias,
    const int* __restrict__ perm, const int4* __restrict__ tiles,
    u16* __restrict__ Hout, float* __restrict__ Fout,
    int K, int N) {
  const int4 ti = tiles[blockIdx.y];
  const int valid = ti.z;
  if (valid == 0) return;
  const int e = ti.x;
  const int base_p = ti.y;
  const int n0 = blockIdx.x * 128;

  __shared__ u16 sA[2 * 128 * 32];   // 16 KB: [half][row][32]
  __shared__ u16 sB[2 * 128 * 32];   // 16 KB

  const int tid = threadIdx.x;
  const int lane = tid & 63;
  const int wave = tid >> 6;
  const int wm = (wave >> 1) * 64;
  const int wn = (wave & 1) * 64;
  const int quad = lane >> 4;
  const int l15 = lane & 15;

  // staging: chunk = 16 rows x 32 elems = 1024 B. wave w stages rows
  // {16w..16w+15, 64+16w..64+16w+15} for both k-halves of A and B.
  const int rr = lane >> 2;           // row within chunk
  const int cb = (lane & 3) * 8;      // elem offset within row-half

  const int rA0 = wave * 16 + rr;
  const int rA1 = rA0 + 64;

  int pa0 = base_p + rA0; if (pa0 > NT - 1) pa0 = NT - 1;   // tail clamp
  int pa1 = base_p + rA1; if (pa1 > NT - 1) pa1 = NT - 1;
  const int arow0 = GATHER_A ? perm[pa0] : pa0;
  const int arow1 = GATHER_A ? perm[pa1] : pa1;
  const u16* aptr0 = A + (size_t)arow0 * K + cb;
  const u16* aptr1 = A + (size_t)arow1 * K + cb;
  const u16* bptr0 = Bt + ((size_t)e * N + n0 + rA0) * K + cb;
  const u16* bptr1 = Bt + ((size_t)e * N + n0 + rA1) * K + cb;

  u16* dA0 = &sA[wave * 512];          // rows 16w..16w+15, half 0
  u16* dA1 = &sA[wave * 512 + 2048];   // rows 64+16w..,   half 0
  u16* dB0 = &sB[wave * 512];
  u16* dB1 = &sB[wave * 512 + 2048];

  f32x4 acc[4][4];
#pragma unroll
  for (int mi = 0; mi < 4; mi++)
#pragma unroll
    for (int ni = 0; ni < 4; ni++)
      acc[mi][ni] = (f32x4){0.f, 0.f, 0.f, 0.f};

  const int kiters = K >> 6;           // BK = 64
  for (int kt = 0; kt < kiters; kt++) {
    if (kt) __syncthreads();           // frags of kt-1 consumed before overwrite
    gl_lds16(aptr0,      dA0);         // half 0
    gl_lds16(aptr1,      dA1);
    gl_lds16(bptr0,      dB0);
    gl_lds16(bptr1,      dB1);
    gl_lds16(aptr0 + 32, dA0 + 4096);  // half 1
    gl_lds16(aptr1 + 32, dA1 + 4096);
    gl_lds16(bptr0 + 32, dB0 + 4096);
    gl_lds16(bptr1 + 32, dB1 + 4096);
    aptr0 += 64; aptr1 += 64; bptr0 += 64; bptr1 += 64;
    __syncthreads();                   // drains vmcnt -> tiles resident

#pragma unroll
    for (int h = 0; h < 2; h++) {
      bf16x8 af[4], bfr[4];
#pragma unroll
      for (int mi = 0; mi < 4; mi++)
        af[mi] = *(const bf16x8*)&sA[h * 4096 + (wm + mi * 16 + l15) * 32 + quad * 8];
#pragma unroll
      for (int ni = 0; ni < 4; ni++)
        bfr[ni] = *(const bf16x8*)&sB[h * 4096 + (wn + ni * 16 + l15) * 32 + quad * 8];
#pragma unroll
      for (int mi = 0; mi < 4; mi++)
#pragma unroll
        for (int ni = 0; ni < 4; ni++)
          acc[mi][ni] = __builtin_amdgcn_mfma_f32_16x16x32_bf16(af[mi], bfr[ni], acc[mi][ni], 0, 0, 0);
    }
  }

  float bv[4];
#pragma unroll
  for (int ni = 0; ni < 4; ni++)
    bv[ni] = bias[(size_t)e * N + n0 + wn + ni * 16 + l15];

  // C/D layout (m89-verified): col = lane&15, row = quad*4 + r
#pragma unroll
  for (int mi = 0; mi < 4; mi++) {
#pragma unroll
    for (int r = 0; r < 4; r++) {
      const int ml = wm + mi * 16 + quad * 4 + r;
      if (ml >= valid) continue;
      const int pp = base_p + ml;
      if (STORE_HIDDEN) {
        u16* orow = Hout + (size_t)pp * N + n0 + wn;
#pragma unroll
        for (int ni = 0; ni < 4; ni++) {
          float v = acc[mi][ni][r] + bv[ni];
          v = v > 0.f ? v : 0.f;
          orow[ni * 16 + l15] = f2b(v);
        }
      } else {
        const int token = perm[pp];
        float* orow = Fout + (size_t)token * N + n0 + wn;
#pragma unroll
        for (int ni = 0; ni < 4; ni++)
          orow[ni * 16 + l15] = acc[mi][ni][r] + bv[ni];
      }
    }
  }
}

__global__ void sentinel_kernel(float* __restrict__ out, int n) {
  int i = blockIdx.x * blockDim.x + threadIdx.x;
  if (i < n) out[i] = 31337.0f;   // diagnoses ws_size too small via absmax
}

extern "C" void kernel_launch(void* const* d_in, const int* in_sizes, int n_in,
                              void* d_out, int out_size, void* d_ws, size_t ws_size,
                              hipStream_t stream) {
  const float* x  = (const float*)d_in[0];
  const float* Wr = (const float*)d_in[1];
  const float* br = (const float*)d_in[2];
  const float* W1 = (const float*)d_in[3];
  const float* b1 = (const float*)d_in[4];
  const float* W2 = (const float*)d_in[5];
  const float* b2 = (const float*)d_in[6];
  float* out = (float*)d_out;

  // workspace layout
  const size_t szXb  = (size_t)NT * DIN * 2;          // 33,554,432
  const size_t szW1t = (size_t)NE * DIN * DHID * 2;   // 67,108,864
  const size_t szW2t = (size_t)NE * DHID * DOUT * 2;  // 67,108,864
  const size_t szHid = (size_t)NT * DHID * 2;         // 134,217,728
  char* ws = (char*)d_ws;
  u16* Xb   = (u16*)ws;
  u16* W1t  = (u16*)(ws + szXb);
  u16* W2t  = (u16*)(ws + szXb + szW1t);
  u16* Hid  = (u16*)(ws + szXb + szW1t + szW2t);
  int* perm = (int*)(ws + szXb + szW1t + szW2t + szHid);
  int* eidx = perm + NT;
  int* ctrl = eidx + NT;          // counts[8] | cursor[8] | offsets[9] | pad | tiles
  int* counts  = ctrl;
  int* cursor  = ctrl + 8;
  int* offsets = ctrl + 16;
  int4* tiles  = (int4*)(ctrl + 32);  // 16B-aligned (ctrl offset is 16B-multiple)
  const size_t NEED = szXb + szW1t + szW2t + szHid + (size_t)NT * 4 * 2 + 4096;

  if (ws_size < NEED) {
    sentinel_kernel<<<(out_size + 255) / 256, 256, 0, stream>>>(out, out_size);
    return;
  }

  zero_kernel<<<1, 64, 0, stream>>>(ctrl);
  transpose_cvt_kernel<<<dim3(DIN / 64, DHID / 64, NE), 256, 0, stream>>>(W1, W1t, DIN, DHID);
  transpose_cvt_kernel<<<dim3(DHID / 64, DOUT / 64, NE), 256, 0, stream>>>(W2, W2t, DHID, DOUT);
  router_kernel<<<NT / 4, 256, 0, stream>>>(x, Wr, br, Xb, eidx, counts);
  scan_kernel<<<1, 64, 0, stream>>>(counts, offsets, tiles);
  scatter_kernel<<<NT / 256, 256, 0, stream>>>(eidx, offsets, cursor, perm);

  // GEMM1: hidden[p][h] = relu(Xb[perm[p]] @ W1[e] + b1[e]), bf16
  moe_gemm<true, true><<<dim3(DHID / 128, NMT), 256, 0, stream>>>(
      Xb, W1t, b1, perm, tiles, Hid, nullptr, DIN, DHID);
  // GEMM2: out[perm[p]][o] = hidden[p] @ W2[e] + b2[e], fp32
  moe_gemm<false, false><<<dim3(DOUT / 128, NMT), 256, 0, stream>>>(
      Hid, W2t, b2, perm, tiles, nullptr, out, DHID, DOUT);
}